// Round 10
// baseline (544.470 us; speedup 1.0000x reference)
//
#include <hip/hip_runtime.h>

// Problem constants: bsx = bsy = 1.0, XL = YL = 0, bin map 1024x1024.
#define NBX 1024
#define NBY 1024
#define TS 64                 // tile size (bins per side)
#define NTX (NBX / TS)        // 16
#define NTY (NBY / TS)        // 16
#define NTILES (NTX * NTY)    // 256
#define LW 66                 // 64 + 2 halo (max window span = 3 bins)
#define LSTRIDE 67
#define CAP 13056             // phys slab cap/tile (mean 11719, +12 sigma)
#define CAPM 11008            // movable slab cap/tile (mean 9766, +12 sigma)
#define HCAP 2048             // halo slab cap/tile (mean ~1510, +12 sigma)

#define FB_BLOCK 512
#define FB_K 8
#define FB_CHUNK (FB_BLOCK * FB_K)   // 4096 -> proven slab run length (~16/tile)

#define PMAP_SCALE 131072.0f
#define PMAP_INV   (1.0f / 131072.0f)

static constexpr int NUM_NODES   = 4000000;
static constexpr int NUM_PHYS    = 3000000;
static constexpr int NUM_MOVABLE = 2500000;
static constexpr int HALF_MOV    = NUM_MOVABLE / 2;

typedef unsigned long long u64;

// ---------------------------------------------------------------------------
// Workspace layout (bytes). pmap region retained for the fallback path only;
// the full path never touches it (B+C fused via per-tile halo slabs).
// ---------------------------------------------------------------------------
static constexpr size_t OFF_PMAP  = 0;                                 // 4 MB
static constexpr size_t OFF_CURS  = OFF_PMAP + (size_t)NBX * NBY * 4;
static constexpr size_t OFF_CURSM = OFF_CURS + NTILES * 4;
static constexpr size_t OFF_CURH  = OFF_CURSM + NTILES * 4;
static constexpr size_t OFF_SLAB  = ((OFF_CURH + NTILES * 4 + 15) / 16) * 16;
static constexpr size_t OFF_MSLAB = ((OFF_SLAB + (size_t)NTILES * CAP * 8 + 15) / 16) * 16;
static constexpr size_t OFF_HSLAB = ((OFF_MSLAB + (size_t)NTILES * CAPM * 12 + 15) / 16) * 16;
static constexpr size_t WS_FULL   = OFF_HSLAB + (size_t)NTILES * HCAP * 8;  // ~69 MB

// ---------------------------------------------------------------------------
// Pass A: fused bucketing with block-local counting sort + coalesced emit.
//   phys payload (8 B): ex:20 | ey:20 | qhx:10 | qhy:10 | pw-1:3  (tile-local,
//     main entries encoded +1; halo entries encoded +2 rel. to TARGET tile)
//   mov  payload (12 B): ex:20 | ey:20 | qsx:12 | qsy:12, + idx (= b0+SO[j])
// Halo duplicates: nodes with tile-local bin in {0,1,62,63} (x or y) are also
// emitted (direct scattered store, ~13% of nodes) into the neighbor tile's
// halo slab so pass B+C can fuse without a pmap round-trip.
// ---------------------------------------------------------------------------
__global__ void __launch_bounds__(FB_BLOCK)
fill_both(const float* __restrict__ pos, const float* __restrict__ nsx,
          const float* __restrict__ nsy, const int* __restrict__ pw,
          unsigned* __restrict__ curs, unsigned* __restrict__ cursm,
          unsigned* __restrict__ curh,
          uint2* __restrict__ slab, uint3* __restrict__ mslab,
          uint2* __restrict__ hslab) {
    __shared__ unsigned cntp[NTILES], cntm[NTILES];
    __shared__ unsigned offp[NTILES], offm[NTILES];
    __shared__ unsigned Dp[NTILES], Dm[NTILES];
    __shared__ unsigned wsum[8];
    __shared__ uint2 SAB[FB_CHUNK];            // 32 KB payload (tile-sorted)
    __shared__ unsigned char  STb[FB_CHUNK];   // 4 KB tile ids (0..255)
    __shared__ unsigned short SO[FB_CHUNK];    // 8 KB within-chunk offsets

    const int tid = threadIdx.x;
    const int b0  = blockIdx.x * FB_CHUNK;

    if (tid < NTILES) { cntp[tid] = 0u; cntm[tid] = 0u; }
    __syncthreads();

    u64 P[FB_K];
    u64 M[FB_K];
    int TPM[FB_K];
    unsigned rkP[FB_K], rkM[FB_K];

    #pragma unroll
    for (int k = 0; k < FB_K; ++k) {
        int i = b0 + k * FB_BLOCK + tid;   // coalesced
        int tp = -1, tm = -1;
        if (i < NUM_PHYS) {
            float mx = pos[i], my = pos[NUM_NODES + i];
            float sx = nsx[i], sy = nsy[i];
            int  pwv = pw[i];
            float hx = 0.5f * fmaxf(1.414f, sx);
            float hy = 0.5f * fmaxf(1.414f, sy);
            unsigned qhx = (unsigned)__float2int_rn((hx - 0.7f) * 1024.0f);
            unsigned qhy = (unsigned)__float2int_rn((hy - 0.7f) * 1024.0f);
            float hxd = 0.7f + (float)qhx * (1.0f / 1024.0f);
            float hyd = 0.7f + (float)qhy * (1.0f / 1024.0f);
            float xmin = mx + 0.5f * sx - hxd;
            float ymin = my + 0.5f * sy - hyd;
            int bxl = min(max((int)floorf(xmin), 0), NBX - 1);
            int byl = min(max((int)floorf(ymin), 0), NBY - 1);
            tp = (bxl >> 6) * NTY + (byl >> 6);
            int bx0 = (tp >> 4) << 6, by0 = (tp & 15) << 6;
            unsigned ex = (unsigned)__float2int_rn((xmin - (float)bx0 + 1.0f) * 8192.0f);
            unsigned ey = (unsigned)__float2int_rn((ymin - (float)by0 + 1.0f) * 8192.0f);
            P[k] = (u64)ex | ((u64)ey << 20) | ((u64)qhx << 40)
                 | ((u64)qhy << 50) | ((u64)(unsigned)(pwv - 1) << 60);
            rkP[k] = atomicAdd(&cntp[tp], 1u);

            // --- halo duplicates into neighbor tiles' windows
            {
                int lx = bxl & 63, ly = byl & 63;
                int dx = (lx < 2) ? -1 : ((lx >= 62) ? 1 : 0);
                int dy = (ly < 2) ? -1 : ((ly >= 62) ? 1 : 0);
                if ((dx | dy) != 0) {
                    int tx = bxl >> 6, ty = byl >> 6;
                    auto emitH = [&](int ttx, int tty) {
                        int tt = ttx * NTY + tty;
                        unsigned exh = (unsigned)__float2int_rn(
                            (xmin - (float)(ttx << 6) + 2.0f) * 8192.0f);
                        unsigned eyh = (unsigned)__float2int_rn(
                            (ymin - (float)(tty << 6) + 2.0f) * 8192.0f);
                        u64 H = (u64)exh | ((u64)eyh << 20) | ((u64)qhx << 40)
                              | ((u64)qhy << 50) | ((u64)(unsigned)(pwv - 1) << 60);
                        unsigned slot = atomicAdd(&curh[tt], 1u);
                        if (slot < HCAP)
                            hslab[(size_t)tt * HCAP + slot] =
                                make_uint2((unsigned)H, (unsigned)(H >> 32));
                    };
                    bool okx = dx && (unsigned)(tx + dx) < (unsigned)NTX;
                    bool oky = dy && (unsigned)(ty + dy) < (unsigned)NTY;
                    if (okx) emitH(tx + dx, ty);
                    if (oky) emitH(tx, ty + dy);
                    if (okx && oky) emitH(tx + dx, ty + dy);
                }
            }

            if (i < NUM_MOVABLE) {
                int bxm = min(max((int)floorf(mx), 0), NBX - 1);
                int bym = min(max((int)floorf(my), 0), NBY - 1);
                tm = (bxm >> 6) * NTY + (bym >> 6);
                int bx0m = (tm >> 4) << 6, by0m = (tm & 15) << 6;
                unsigned exm = (unsigned)__float2int_rn((mx - (float)bx0m) * 8192.0f);
                unsigned eym = (unsigned)__float2int_rn((my - (float)by0m) * 8192.0f);
                unsigned qsx = (unsigned)__float2int_rn((sx - 0.5f) * 2048.0f);
                unsigned qsy = (unsigned)__float2int_rn((sy - 0.5f) * 2048.0f);
                M[k] = (u64)exm | ((u64)eym << 20) | ((u64)qsx << 40) | ((u64)qsy << 52);
                rkM[k] = atomicAdd(&cntm[tm], 1u);
            }
        }
        TPM[k] = (tp & 0xffff) | (tm << 16);
    }
    __syncthreads();

    // --- 256-entry exclusive scans: phys on waves 0-3, movable on waves 4-7.
    {
        const int lane   = tid & 63;
        const int scanId = tid & 255;
        const bool isMov = tid >= 256;

        unsigned v = isMov ? cntm[scanId] : cntp[scanId];
        unsigned x = v;
        #pragma unroll
        for (int d = 1; d < 64; d <<= 1) {
            unsigned y = __shfl_up(x, d);
            if (lane >= d) x += y;
        }
        if (lane == 63) wsum[tid >> 6] = x;
        __syncthreads();
        unsigned add = 0;
        const int w0 = isMov ? 4 : 0;
        for (int w = 0; w < (scanId >> 6); ++w) add += wsum[w0 + w];
        unsigned o = x + add - v;                 // exclusive prefix
        unsigned* gc = isMov ? cursm : curs;
        unsigned base = v ? atomicAdd(&gc[scanId], v) : 0u;
        if (isMov) { offm[scanId] = o; Dm[scanId] = base - o; }
        else       { offp[scanId] = o; Dp[scanId] = base - o; }
    }
    __syncthreads();

    // --- stage phys tile-sorted
    #pragma unroll
    for (int k = 0; k < FB_K; ++k) {
        int tp = (int)(short)(TPM[k] & 0xffff);
        if (tp >= 0) {
            unsigned s = offp[tp] + rkP[k];
            SAB[s] = make_uint2((unsigned)P[k], (unsigned)(P[k] >> 32));
            STb[s] = (unsigned char)tp;
        }
    }
    __syncthreads();

    // --- coalesced phys emit: consecutive j -> contiguous slab runs
    {
        unsigned tot = offp[NTILES - 1] + cntp[NTILES - 1];
        for (unsigned j = tid; j < tot; j += FB_BLOCK) {
            unsigned tile = STb[j];
            unsigned p = Dp[tile] + j;
            if (p < CAP)
                slab[(size_t)tile * CAP + p] = SAB[j];
        }
    }
    __syncthreads();

    // --- stage movable tile-sorted (reuse LDS)
    #pragma unroll
    for (int k = 0; k < FB_K; ++k) {
        int tm = TPM[k] >> 16;
        if (tm >= 0) {
            unsigned s = offm[tm] + rkM[k];
            SAB[s] = make_uint2((unsigned)M[k], (unsigned)(M[k] >> 32));
            SO[s]  = (unsigned short)(k * FB_BLOCK + tid);
            STb[s] = (unsigned char)tm;
        }
    }
    __syncthreads();

    // --- coalesced movable emit
    {
        unsigned tot = offm[NTILES - 1] + cntm[NTILES - 1];
        for (unsigned j = tid; j < tot; j += FB_BLOCK) {
            unsigned tile = STb[j];
            unsigned p = Dm[tile] + j;
            if (p < CAPM) {
                uint2 ab = SAB[j];
                mslab[(size_t)tile * CAPM + p] =
                    make_uint3(ab.x, ab.y, (unsigned)(b0 + SO[j]));
            }
        }
    }
}

// ---------------------------------------------------------------------------
// Fused pass B+C: one block per tile. Accumulate own slab + halo slab into
// fixed-point u32 LDS (ds_add_u32), convert in-place to clamped adj, gather
// movables. No pmap: no global atomic flush, no read-back, no zeroing, one
// less launch+drain.
// ---------------------------------------------------------------------------
__global__ void __launch_bounds__(1024)
fused_bc(const uint2* __restrict__ slab, const unsigned* __restrict__ curs,
         const uint2* __restrict__ hslab, const unsigned* __restrict__ curh,
         const uint3* __restrict__ mslab, const unsigned* __restrict__ cursm,
         float* __restrict__ out) {
    __shared__ unsigned lds[LW * LSTRIDE];   // 17.7 KB (u32 acc, then float adj)
    const int t   = blockIdx.x;
    const int tid = threadIdx.x;

    for (int c = tid; c < LW * LSTRIDE; c += 1024) lds[c] = 0u;
    __syncthreads();

    // --- main accumulate (encoding +1; window rows/cols 0..65)
    {
        unsigned n = min(curs[t], (unsigned)CAP);
        const uint2* sl = slab + (size_t)t * CAP;
        unsigned k = tid;
        uint2 p = (k < n) ? sl[k] : make_uint2(0u, 0u);
        while (k < n) {
            unsigned kn = k + 1024;
            uint2 pn = (kn < n) ? sl[kn] : make_uint2(0u, 0u);

            u64 P = (u64)p.x | ((u64)p.y << 32);
            float xminl = (float)(P & 0xFFFFFu)         * (1.0f / 8192.0f) - 1.0f;
            float yminl = (float)((P >> 20) & 0xFFFFFu) * (1.0f / 8192.0f) - 1.0f;
            float hx = 0.7f + (float)((P >> 40) & 0x3FFu) * (1.0f / 1024.0f);
            float hy = 0.7f + (float)((P >> 50) & 0x3FFu) * (1.0f / 1024.0f);
            float pwv  = (float)(1u + (unsigned)(P >> 60));
            float dens = pwv / (4.0f * hx * hy);
            float xmaxl = xminl + 2.0f * hx;
            float ymaxl = yminl + 2.0f * hy;

            int lx0 = min(max((int)floorf(xminl), 0), TS - 1);
            int ly0 = min(max((int)floorf(yminl), 0), TS - 1);
            #pragma unroll
            for (int di = 0; di < 3; ++di) {
                float bl = (float)(lx0 + di);
                float ox = fminf(xmaxl, bl + 1.0f) - fmaxf(xminl, bl);
                if (ox <= 0.0f) continue;
                float dox = dens * ox;
                #pragma unroll
                for (int dj = 0; dj < 3; ++dj) {
                    float bly = (float)(ly0 + dj);
                    float oy  = fminf(ymaxl, bly + 1.0f) - fmaxf(yminl, bly);
                    if (oy > 0.0f) {
                        unsigned q = (unsigned)__float2int_rn(dox * oy * PMAP_SCALE);
                        atomicAdd(&lds[(lx0 + di) * LSTRIDE + (ly0 + dj)], q);
                    }
                }
            }
            p = pn;
            k = kn;
        }
    }

    // --- halo accumulate (encoding +2 rel. to this tile; clip to window)
    {
        unsigned n = min(curh[t], (unsigned)HCAP);
        const uint2* hl = hslab + (size_t)t * HCAP;
        for (unsigned k = tid; k < n; k += 1024) {
            uint2 p = hl[k];
            u64 P = (u64)p.x | ((u64)p.y << 32);
            float xminl = (float)(P & 0xFFFFFu)         * (1.0f / 8192.0f) - 2.0f;
            float yminl = (float)((P >> 20) & 0xFFFFFu) * (1.0f / 8192.0f) - 2.0f;
            float hx = 0.7f + (float)((P >> 40) & 0x3FFu) * (1.0f / 1024.0f);
            float hy = 0.7f + (float)((P >> 50) & 0x3FFu) * (1.0f / 1024.0f);
            float pwv  = (float)(1u + (unsigned)(P >> 60));
            float dens = pwv / (4.0f * hx * hy);
            float xmaxl = xminl + 2.0f * hx;
            float ymaxl = yminl + 2.0f * hy;

            int lx0 = (int)floorf(xminl);   // in [-2, 65]
            int ly0 = (int)floorf(yminl);
            #pragma unroll
            for (int di = 0; di < 3; ++di) {
                int r = lx0 + di;
                if ((unsigned)r >= (unsigned)LW) continue;   // outside window
                float bl = (float)r;
                float ox = fminf(xmaxl, bl + 1.0f) - fmaxf(xminl, bl);
                if (ox <= 0.0f) continue;
                float dox = dens * ox;
                #pragma unroll
                for (int dj = 0; dj < 3; ++dj) {
                    int cc = ly0 + dj;
                    if ((unsigned)cc >= (unsigned)LW) continue;
                    float bly = (float)cc;
                    float oy  = fminf(ymaxl, bly + 1.0f) - fmaxf(yminl, bly);
                    if (oy > 0.0f) {
                        unsigned q = (unsigned)__float2int_rn(dox * oy * PMAP_SCALE);
                        atomicAdd(&lds[r * LSTRIDE + cc], q);
                    }
                }
            }
        }
    }
    __syncthreads();

    // --- convert fixed-point density -> clamped adj, in place
    float* adjf = (float*)lds;
    for (int c = tid; c < LW * LSTRIDE; c += 1024) {
        float v = (float)lds[c] * PMAP_INV;
        adjf[c] = fminf(fmaxf(v * 0.5f, 0.4f), 2.5f);
    }
    __syncthreads();

    // --- gather movables
    {
        unsigned n = min(cursm[t], (unsigned)CAPM);
        const uint3* sl = mslab + (size_t)t * CAPM;
        for (unsigned k = tid; k < n; k += 1024) {
            uint3 p = sl[k];
            u64 M = (u64)p.x | ((u64)p.y << 32);
            float mxl = (float)(M & 0xFFFFFu)         * (1.0f / 8192.0f);
            float myl = (float)((M >> 20) & 0xFFFFFu) * (1.0f / 8192.0f);
            float sx  = 0.5f + (float)((M >> 40) & 0xFFFu) * (1.0f / 2048.0f);
            float sy  = 0.5f + (float)(M >> 52)            * (1.0f / 2048.0f);
            float xmaxl = mxl + sx;
            float ymaxl = myl + sy;

            int lx0 = min((int)mxl, TS - 1);
            int ly0 = min((int)myl, TS - 1);

            float area = 0.0f;
            #pragma unroll
            for (int di = 0; di < 3; ++di) {
                float bl = (float)(lx0 + di);
                float ox = fmaxf(fminf(xmaxl, bl + 1.0f) - fmaxf(mxl, bl), 0.0f);
                #pragma unroll
                for (int dj = 0; dj < 3; ++dj) {
                    float bly = (float)(ly0 + dj);
                    float oy  = fmaxf(fminf(ymaxl, bly + 1.0f) - fmaxf(myl, bly), 0.0f);
                    area += ox * oy * adjf[(lx0 + di) * LSTRIDE + (ly0 + dj)];
                }
            }
            out[p.z] = area;
        }
    }
}

// ---------------------------------------------------------------------------
// Fallback path (tiny workspace): direct global-atomic scatter + direct gather
// ---------------------------------------------------------------------------
__global__ void __launch_bounds__(256)
scatter_pin(const float* __restrict__ pos, const float* __restrict__ nsx,
            const float* __restrict__ nsy, const int* __restrict__ pw,
            float* __restrict__ pmap) {
    int i = blockIdx.x * blockDim.x + threadIdx.x;
    if (i >= NUM_PHYS) return;
    float sx = nsx[i], sy = nsy[i];
    float hx = 0.5f * fmaxf(1.414f, sx);
    float hy = 0.5f * fmaxf(1.414f, sy);
    float cx = pos[i] + 0.5f * sx;
    float cy = pos[NUM_NODES + i] + 0.5f * sy;
    float xmin = cx - hx, xmax = cx + hx;
    float ymin = cy - hy, ymax = cy + hy;
    float dens = (float)pw[i] / (4.0f * hx * hy);
    int bxl = min(max((int)floorf(xmin), 0), NBX - 1);
    int byl = min(max((int)floorf(ymin), 0), NBY - 1);
    #pragma unroll
    for (int di = 0; di < 3; ++di) {
        float bl = (float)(bxl + di);
        float ox = fminf(xmax, bl + 1.0f) - fmaxf(xmin, bl);
        if (ox <= 0.0f) continue;
        float dox = dens * ox;
        int base = min(bxl + di, NBX - 1) * NBY;
        #pragma unroll
        for (int dj = 0; dj < 3; ++dj) {
            float bly = (float)(byl + dj);
            float oy  = fminf(ymax, bly + 1.0f) - fmaxf(ymin, bly);
            if (oy > 0.0f) atomicAdd(&pmap[base + min(byl + dj, NBY - 1)], dox * oy);
        }
    }
}

__device__ __forceinline__ float gather_one(const float* __restrict__ pos,
                                            const float* __restrict__ nsx,
                                            const float* __restrict__ nsy,
                                            const float* __restrict__ pmap,
                                            int i) {
    float mx = pos[i];
    float my = pos[NUM_NODES + i];
    float xmax = mx + nsx[i];
    float ymax = my + nsy[i];
    int bxl = min(max((int)floorf(mx), 0), NBX - 1);
    int byl = min(max((int)floorf(my), 0), NBY - 1);
    float ox[3], oy[3];
    int rowb[3], colb[3];
    #pragma unroll
    for (int d = 0; d < 3; ++d) {
        float bl  = (float)(bxl + d);
        float bly = (float)(byl + d);
        ox[d] = fmaxf(fminf(xmax, bl + 1.0f) - fmaxf(mx, bl), 0.0f);
        oy[d] = fmaxf(fminf(ymax, bly + 1.0f) - fmaxf(my, bly), 0.0f);
        rowb[d] = min(bxl + d, NBX - 1) * NBY;
        colb[d] = min(byl + d, NBY - 1);
    }
    float area = 0.0f;
    #pragma unroll
    for (int di = 0; di < 3; ++di)
        #pragma unroll
        for (int dj = 0; dj < 3; ++dj) {
            float a = fminf(fmaxf(pmap[rowb[di] + colb[dj]] * 0.5f, 0.4f), 2.5f);
            area += ox[di] * oy[dj] * a;
        }
    return area;
}

__global__ void __launch_bounds__(256)
gather_area(const float* __restrict__ pos, const float* __restrict__ nsx,
            const float* __restrict__ nsy, const float* __restrict__ pmap,
            float* __restrict__ out) {
    int i = blockIdx.x * blockDim.x + threadIdx.x;
    if (i >= HALF_MOV) return;
    int i2 = i + HALF_MOV;
    float a1 = gather_one(pos, nsx, nsy, pmap, i);
    float a2 = gather_one(pos, nsx, nsy, pmap, i2);
    out[i]  = a1;
    out[i2] = a2;
}

// ---------------------------------------------------------------------------
extern "C" void kernel_launch(void* const* d_in, const int* in_sizes, int n_in,
                              void* d_out, int out_size, void* d_ws, size_t ws_size,
                              hipStream_t stream) {
    const float* pos = (const float*)d_in[0];
    const float* nsx = (const float*)d_in[1];
    const float* nsy = (const float*)d_in[2];
    const int*   pw  = (const int*)d_in[3];
    float* out = (float*)d_out;

    char* ws = (char*)d_ws;
    float*    pmap  = (float*)(ws + OFF_PMAP);
    unsigned* curs  = (unsigned*)(ws + OFF_CURS);
    unsigned* cursm = (unsigned*)(ws + OFF_CURSM);
    unsigned* curh  = (unsigned*)(ws + OFF_CURH);
    uint2*    slab  = (uint2*)(ws + OFF_SLAB);
    uint3*    mslab = (uint3*)(ws + OFF_MSLAB);
    uint2*    hslab = (uint2*)(ws + OFF_HSLAB);

    if (ws_size >= WS_FULL) {
        // zero the three cursor arrays only (3 KB)
        hipMemsetAsync(ws + OFF_CURS, 0, OFF_SLAB - OFF_CURS, stream);
        int grid = (NUM_PHYS + FB_CHUNK - 1) / FB_CHUNK;   // 733
        fill_both<<<grid, FB_BLOCK, 0, stream>>>(pos, nsx, nsy, pw,
                                                 curs, cursm, curh,
                                                 slab, mslab, hslab);
        fused_bc <<<NTILES, 1024, 0, stream>>>(slab, curs, hslab, curh,
                                               mslab, cursm, out);
    } else {
        hipMemsetAsync(pmap, 0, (size_t)NBX * NBY * sizeof(float), stream);
        scatter_pin <<<(NUM_PHYS + 255) / 256, 256, 0, stream>>>(pos, nsx, nsy, pw, pmap);
        gather_area <<<(HALF_MOV + 255) / 256, 256, 0, stream>>>(pos, nsx, nsy, pmap, out);
    }
}

// Round 11
// 180.664 us; speedup vs baseline: 3.0137x; 3.0137x over previous
//
#include <hip/hip_runtime.h>

// Problem constants: bsx = bsy = 1.0, XL = YL = 0, bin map 1024x1024.
#define NBX 1024
#define NBY 1024
#define TS 64                 // tile size (bins per side)
#define NTX (NBX / TS)        // 16
#define NTY (NBY / TS)        // 16
#define NTILES (NTX * NTY)    // 256
#define LW 66                 // 64 + 2 halo (max window span = 3 bins)
#define LSTRIDE 67
#define CAP 13056             // phys slab cap/tile (mean 11719, +12 sigma)
#define CAPM 11008            // movable slab cap/tile (mean 9766, +12 sigma)
#define HCAP 2048             // halo slab cap/tile (mean ~1510, +13 sigma)

#define FB_BLOCK 512
#define FB_K 8
#define FB_CHUNK (FB_BLOCK * FB_K)   // 4096 -> proven slab run length (~16/tile)

#define PMAP_SCALE 131072.0f
#define PMAP_INV   (1.0f / 131072.0f)

static constexpr int NUM_NODES   = 4000000;
static constexpr int NUM_PHYS    = 3000000;
static constexpr int NUM_MOVABLE = 2500000;
static constexpr int HALF_MOV    = NUM_MOVABLE / 2;

typedef unsigned long long u64;

// ---------------------------------------------------------------------------
// Workspace layout (bytes). pmap region retained for the fallback path only.
// ---------------------------------------------------------------------------
static constexpr size_t OFF_PMAP  = 0;                                 // 4 MB
static constexpr size_t OFF_CURS  = OFF_PMAP + (size_t)NBX * NBY * 4;
static constexpr size_t OFF_CURSM = OFF_CURS + NTILES * 4;
static constexpr size_t OFF_CURH  = OFF_CURSM + NTILES * 4;
static constexpr size_t OFF_SLAB  = ((OFF_CURH + NTILES * 4 + 15) / 16) * 16;
static constexpr size_t OFF_MSLAB = ((OFF_SLAB + (size_t)NTILES * CAP * 8 + 15) / 16) * 16;
static constexpr size_t OFF_HSLAB = ((OFF_MSLAB + (size_t)NTILES * CAPM * 12 + 15) / 16) * 16;
static constexpr size_t WS_FULL   = OFF_HSLAB + (size_t)NTILES * HCAP * 8;  // ~69 MB

// ---------------------------------------------------------------------------
// Pass A: fused bucketing with block-local counting sort + coalesced emit.
//   phys payload (8 B): ex:20 | ey:20 | qhx:10 | qhy:10 | pw-1:3  (tile-local,
//     main entries encoded +1; halo entries encoded +2 rel. to TARGET tile)
//   mov  payload (12 B): ex:20 | ey:20 | qsx:12 | qsy:12, + idx (= b0+SO[j])
// Halo counts are AGGREGATED: LDS histogram -> ONE global atomic per
// (block,tile) in the scan phase -> rank via LDS counter in phase-2 emit.
// (R10's per-node returning global atomics on 256 counters = 414 us stall.)
// Halo payload rebuilt from P[k] by integer offsets: exh = ex+8192-dx*524288.
// ---------------------------------------------------------------------------
__global__ void __launch_bounds__(FB_BLOCK)
fill_both(const float* __restrict__ pos, const float* __restrict__ nsx,
          const float* __restrict__ nsy, const int* __restrict__ pw,
          unsigned* __restrict__ curs, unsigned* __restrict__ cursm,
          unsigned* __restrict__ curh,
          uint2* __restrict__ slab, uint3* __restrict__ mslab,
          uint2* __restrict__ hslab) {
    __shared__ unsigned cntp[NTILES], cntm[NTILES], cnth[NTILES];
    __shared__ unsigned offp[NTILES], offm[NTILES];
    __shared__ unsigned Dp[NTILES], Dm[NTILES], Dh[NTILES];
    __shared__ unsigned wsum[8];
    __shared__ uint2 SAB[FB_CHUNK];            // 32 KB payload (tile-sorted)
    __shared__ unsigned char  STb[FB_CHUNK];   // 4 KB tile ids (0..255)
    __shared__ unsigned short SO[FB_CHUNK];    // 8 KB within-chunk offsets

    const int tid = threadIdx.x;
    const int b0  = blockIdx.x * FB_CHUNK;

    if (tid < NTILES) { cntp[tid] = 0u; cntm[tid] = 0u; cnth[tid] = 0u; }
    __syncthreads();

    u64 P[FB_K];
    u64 M[FB_K];
    int TPM[FB_K];
    unsigned rkP[FB_K], rkM[FB_K];
    unsigned char HK[FB_K];                    // halo flags: 1=+x 2=-x 4=+y 8=-y

    #pragma unroll
    for (int k = 0; k < FB_K; ++k) {
        int i = b0 + k * FB_BLOCK + tid;   // coalesced
        int tp = -1, tm = -1;
        unsigned hc = 0;
        if (i < NUM_PHYS) {
            float mx = pos[i], my = pos[NUM_NODES + i];
            float sx = nsx[i], sy = nsy[i];
            int  pwv = pw[i];
            float hx = 0.5f * fmaxf(1.414f, sx);
            float hy = 0.5f * fmaxf(1.414f, sy);
            unsigned qhx = (unsigned)__float2int_rn((hx - 0.7f) * 1024.0f);
            unsigned qhy = (unsigned)__float2int_rn((hy - 0.7f) * 1024.0f);
            float hxd = 0.7f + (float)qhx * (1.0f / 1024.0f);
            float hyd = 0.7f + (float)qhy * (1.0f / 1024.0f);
            float xmin = mx + 0.5f * sx - hxd;
            float ymin = my + 0.5f * sy - hyd;
            int bxl = min(max((int)floorf(xmin), 0), NBX - 1);
            int byl = min(max((int)floorf(ymin), 0), NBY - 1);
            tp = (bxl >> 6) * NTY + (byl >> 6);
            int bx0 = (tp >> 4) << 6, by0 = (tp & 15) << 6;
            unsigned ex = (unsigned)__float2int_rn((xmin - (float)bx0 + 1.0f) * 8192.0f);
            unsigned ey = (unsigned)__float2int_rn((ymin - (float)by0 + 1.0f) * 8192.0f);
            P[k] = (u64)ex | ((u64)ey << 20) | ((u64)qhx << 40)
                 | ((u64)qhy << 50) | ((u64)(unsigned)(pwv - 1) << 60);
            rkP[k] = atomicAdd(&cntp[tp], 1u);

            // --- halo histogram (LDS only; no global atomics here)
            {
                int lx = bxl & 63, ly = byl & 63;
                int dx = (lx < 2) ? -1 : ((lx >= 62) ? 1 : 0);
                int dy = (ly < 2) ? -1 : ((ly >= 62) ? 1 : 0);
                int tx = bxl >> 6, ty = byl >> 6;
                bool okx = dx && ((unsigned)(tx + dx) < (unsigned)NTX);
                bool oky = dy && ((unsigned)(ty + dy) < (unsigned)NTY);
                if (okx) { hc |= (dx > 0) ? 1u : 2u;
                           atomicAdd(&cnth[(tx + dx) * NTY + ty], 1u); }
                if (oky) { hc |= (dy > 0) ? 4u : 8u;
                           atomicAdd(&cnth[tx * NTY + ty + dy], 1u); }
                if (okx && oky)
                           atomicAdd(&cnth[(tx + dx) * NTY + ty + dy], 1u);
            }

            if (i < NUM_MOVABLE) {
                int bxm = min(max((int)floorf(mx), 0), NBX - 1);
                int bym = min(max((int)floorf(my), 0), NBY - 1);
                tm = (bxm >> 6) * NTY + (bym >> 6);
                int bx0m = (tm >> 4) << 6, by0m = (tm & 15) << 6;
                unsigned exm = (unsigned)__float2int_rn((mx - (float)bx0m) * 8192.0f);
                unsigned eym = (unsigned)__float2int_rn((my - (float)by0m) * 8192.0f);
                unsigned qsx = (unsigned)__float2int_rn((sx - 0.5f) * 2048.0f);
                unsigned qsy = (unsigned)__float2int_rn((sy - 0.5f) * 2048.0f);
                M[k] = (u64)exm | ((u64)eym << 20) | ((u64)qsx << 40) | ((u64)qsy << 52);
                rkM[k] = atomicAdd(&cntm[tm], 1u);
            }
        }
        TPM[k] = (tp & 0xffff) | (tm << 16);
        HK[k]  = (unsigned char)hc;
    }
    __syncthreads();

    // --- 256-entry exclusive scans: phys on waves 0-3, movable on waves 4-7.
    //     Halo needs no scan: one aggregated global atomic per tile.
    {
        const int lane   = tid & 63;
        const int scanId = tid & 255;
        const bool isMov = tid >= 256;

        unsigned v = isMov ? cntm[scanId] : cntp[scanId];
        unsigned x = v;
        #pragma unroll
        for (int d = 1; d < 64; d <<= 1) {
            unsigned y = __shfl_up(x, d);
            if (lane >= d) x += y;
        }
        if (lane == 63) wsum[tid >> 6] = x;
        __syncthreads();
        unsigned add = 0;
        const int w0 = isMov ? 4 : 0;
        for (int w = 0; w < (scanId >> 6); ++w) add += wsum[w0 + w];
        unsigned o = x + add - v;                 // exclusive prefix
        unsigned* gc = isMov ? cursm : curs;
        unsigned base = v ? atomicAdd(&gc[scanId], v) : 0u;
        if (isMov) { offm[scanId] = o; Dm[scanId] = base - o; }
        else       { offp[scanId] = o; Dp[scanId] = base - o; }
        if (tid < NTILES) {
            unsigned hv = cnth[tid];
            Dh[tid] = hv ? atomicAdd(&curh[tid], hv) : 0u;
            cnth[tid] = 0u;                       // reset -> phase-2 rank ctr
        }
    }
    __syncthreads();

    // --- halo emit (scattered, ~600 stores/block; ranks via LDS atomic)
    #pragma unroll
    for (int k = 0; k < FB_K; ++k) {
        unsigned hc = HK[k];
        if (hc) {
            int tp = (int)(short)(TPM[k] & 0xffff);
            int tx = tp >> 4, ty = tp & 15;
            unsigned ex = (unsigned)(P[k] & 0xFFFFFu);
            unsigned ey = (unsigned)((P[k] >> 20) & 0xFFFFFu);
            u64 hi = P[k] & 0xFFFFFF0000000000ull;   // qhx,qhy,pw bits
            int dx = (hc & 1u) ? 1 : ((hc & 2u) ? -1 : 0);
            int dy = (hc & 4u) ? 1 : ((hc & 8u) ? -1 : 0);
            unsigned ex0 = ex + 8192u;
            unsigned ey0 = ey + 8192u;
            unsigned exS = (unsigned)((int)ex + 8192 - dx * 524288);
            unsigned eyS = (unsigned)((int)ey + 8192 - dy * 524288);
            if (dx) {
                int tt = (tx + dx) * NTY + ty;
                unsigned slot = Dh[tt] + atomicAdd(&cnth[tt], 1u);
                u64 H = hi | exS | ((u64)ey0 << 20);
                if (slot < HCAP)
                    hslab[(size_t)tt * HCAP + slot] =
                        make_uint2((unsigned)H, (unsigned)(H >> 32));
            }
            if (dy) {
                int tt = tx * NTY + ty + dy;
                unsigned slot = Dh[tt] + atomicAdd(&cnth[tt], 1u);
                u64 H = hi | ex0 | ((u64)eyS << 20);
                if (slot < HCAP)
                    hslab[(size_t)tt * HCAP + slot] =
                        make_uint2((unsigned)H, (unsigned)(H >> 32));
            }
            if (dx && dy) {
                int tt = (tx + dx) * NTY + ty + dy;
                unsigned slot = Dh[tt] + atomicAdd(&cnth[tt], 1u);
                u64 H = hi | exS | ((u64)eyS << 20);
                if (slot < HCAP)
                    hslab[(size_t)tt * HCAP + slot] =
                        make_uint2((unsigned)H, (unsigned)(H >> 32));
            }
        }
    }

    // --- stage phys tile-sorted
    #pragma unroll
    for (int k = 0; k < FB_K; ++k) {
        int tp = (int)(short)(TPM[k] & 0xffff);
        if (tp >= 0) {
            unsigned s = offp[tp] + rkP[k];
            SAB[s] = make_uint2((unsigned)P[k], (unsigned)(P[k] >> 32));
            STb[s] = (unsigned char)tp;
        }
    }
    __syncthreads();

    // --- coalesced phys emit: consecutive j -> contiguous slab runs
    {
        unsigned tot = offp[NTILES - 1] + cntp[NTILES - 1];
        for (unsigned j = tid; j < tot; j += FB_BLOCK) {
            unsigned tile = STb[j];
            unsigned p = Dp[tile] + j;
            if (p < CAP)
                slab[(size_t)tile * CAP + p] = SAB[j];
        }
    }
    __syncthreads();

    // --- stage movable tile-sorted (reuse LDS)
    #pragma unroll
    for (int k = 0; k < FB_K; ++k) {
        int tm = TPM[k] >> 16;
        if (tm >= 0) {
            unsigned s = offm[tm] + rkM[k];
            SAB[s] = make_uint2((unsigned)M[k], (unsigned)(M[k] >> 32));
            SO[s]  = (unsigned short)(k * FB_BLOCK + tid);
            STb[s] = (unsigned char)tm;
        }
    }
    __syncthreads();

    // --- coalesced movable emit
    {
        unsigned tot = offm[NTILES - 1] + cntm[NTILES - 1];
        for (unsigned j = tid; j < tot; j += FB_BLOCK) {
            unsigned tile = STb[j];
            unsigned p = Dm[tile] + j;
            if (p < CAPM) {
                uint2 ab = SAB[j];
                mslab[(size_t)tile * CAPM + p] =
                    make_uint3(ab.x, ab.y, (unsigned)(b0 + SO[j]));
            }
        }
    }
}

// ---------------------------------------------------------------------------
// Fused pass B+C: one block per tile. Accumulate own slab + halo slab into
// fixed-point u32 LDS (ds_add_u32), convert in-place to clamped adj, gather
// movables. No pmap: no global atomic flush, no read-back, no zeroing.
// ---------------------------------------------------------------------------
__global__ void __launch_bounds__(1024)
fused_bc(const uint2* __restrict__ slab, const unsigned* __restrict__ curs,
         const uint2* __restrict__ hslab, const unsigned* __restrict__ curh,
         const uint3* __restrict__ mslab, const unsigned* __restrict__ cursm,
         float* __restrict__ out) {
    __shared__ unsigned lds[LW * LSTRIDE];   // 17.7 KB (u32 acc, then float adj)
    const int t   = blockIdx.x;
    const int tid = threadIdx.x;

    for (int c = tid; c < LW * LSTRIDE; c += 1024) lds[c] = 0u;
    __syncthreads();

    // --- main accumulate (encoding +1; window rows/cols 0..65)
    {
        unsigned n = min(curs[t], (unsigned)CAP);
        const uint2* sl = slab + (size_t)t * CAP;
        unsigned k = tid;
        uint2 p = (k < n) ? sl[k] : make_uint2(0u, 0u);
        while (k < n) {
            unsigned kn = k + 1024;
            uint2 pn = (kn < n) ? sl[kn] : make_uint2(0u, 0u);

            u64 P = (u64)p.x | ((u64)p.y << 32);
            float xminl = (float)(P & 0xFFFFFu)         * (1.0f / 8192.0f) - 1.0f;
            float yminl = (float)((P >> 20) & 0xFFFFFu) * (1.0f / 8192.0f) - 1.0f;
            float hx = 0.7f + (float)((P >> 40) & 0x3FFu) * (1.0f / 1024.0f);
            float hy = 0.7f + (float)((P >> 50) & 0x3FFu) * (1.0f / 1024.0f);
            float pwv  = (float)(1u + (unsigned)(P >> 60));
            float dens = pwv / (4.0f * hx * hy);
            float xmaxl = xminl + 2.0f * hx;
            float ymaxl = yminl + 2.0f * hy;

            int lx0 = min(max((int)floorf(xminl), 0), TS - 1);
            int ly0 = min(max((int)floorf(yminl), 0), TS - 1);
            #pragma unroll
            for (int di = 0; di < 3; ++di) {
                float bl = (float)(lx0 + di);
                float ox = fminf(xmaxl, bl + 1.0f) - fmaxf(xminl, bl);
                if (ox <= 0.0f) continue;
                float dox = dens * ox;
                #pragma unroll
                for (int dj = 0; dj < 3; ++dj) {
                    float bly = (float)(ly0 + dj);
                    float oy  = fminf(ymaxl, bly + 1.0f) - fmaxf(yminl, bly);
                    if (oy > 0.0f) {
                        unsigned q = (unsigned)__float2int_rn(dox * oy * PMAP_SCALE);
                        atomicAdd(&lds[(lx0 + di) * LSTRIDE + (ly0 + dj)], q);
                    }
                }
            }
            p = pn;
            k = kn;
        }
    }

    // --- halo accumulate (encoding +2 rel. to this tile; clip to window)
    {
        unsigned n = min(curh[t], (unsigned)HCAP);
        const uint2* hl = hslab + (size_t)t * HCAP;
        for (unsigned k = tid; k < n; k += 1024) {
            uint2 p = hl[k];
            u64 P = (u64)p.x | ((u64)p.y << 32);
            float xminl = (float)(P & 0xFFFFFu)         * (1.0f / 8192.0f) - 2.0f;
            float yminl = (float)((P >> 20) & 0xFFFFFu) * (1.0f / 8192.0f) - 2.0f;
            float hx = 0.7f + (float)((P >> 40) & 0x3FFu) * (1.0f / 1024.0f);
            float hy = 0.7f + (float)((P >> 50) & 0x3FFu) * (1.0f / 1024.0f);
            float pwv  = (float)(1u + (unsigned)(P >> 60));
            float dens = pwv / (4.0f * hx * hy);
            float xmaxl = xminl + 2.0f * hx;
            float ymaxl = yminl + 2.0f * hy;

            int lx0 = (int)floorf(xminl);   // in [-2, 65]
            int ly0 = (int)floorf(yminl);
            #pragma unroll
            for (int di = 0; di < 3; ++di) {
                int r = lx0 + di;
                if ((unsigned)r >= (unsigned)LW) continue;   // outside window
                float bl = (float)r;
                float ox = fminf(xmaxl, bl + 1.0f) - fmaxf(xminl, bl);
                if (ox <= 0.0f) continue;
                float dox = dens * ox;
                #pragma unroll
                for (int dj = 0; dj < 3; ++dj) {
                    int cc = ly0 + dj;
                    if ((unsigned)cc >= (unsigned)LW) continue;
                    float bly = (float)cc;
                    float oy  = fminf(ymaxl, bly + 1.0f) - fmaxf(yminl, bly);
                    if (oy > 0.0f) {
                        unsigned q = (unsigned)__float2int_rn(dox * oy * PMAP_SCALE);
                        atomicAdd(&lds[r * LSTRIDE + cc], q);
                    }
                }
            }
        }
    }
    __syncthreads();

    // --- convert fixed-point density -> clamped adj, in place
    float* adjf = (float*)lds;
    for (int c = tid; c < LW * LSTRIDE; c += 1024) {
        float v = (float)lds[c] * PMAP_INV;
        adjf[c] = fminf(fmaxf(v * 0.5f, 0.4f), 2.5f);
    }
    __syncthreads();

    // --- gather movables
    {
        unsigned n = min(cursm[t], (unsigned)CAPM);
        const uint3* sl = mslab + (size_t)t * CAPM;
        for (unsigned k = tid; k < n; k += 1024) {
            uint3 p = sl[k];
            u64 M = (u64)p.x | ((u64)p.y << 32);
            float mxl = (float)(M & 0xFFFFFu)         * (1.0f / 8192.0f);
            float myl = (float)((M >> 20) & 0xFFFFFu) * (1.0f / 8192.0f);
            float sx  = 0.5f + (float)((M >> 40) & 0xFFFu) * (1.0f / 2048.0f);
            float sy  = 0.5f + (float)(M >> 52)            * (1.0f / 2048.0f);
            float xmaxl = mxl + sx;
            float ymaxl = myl + sy;

            int lx0 = min((int)mxl, TS - 1);
            int ly0 = min((int)myl, TS - 1);

            float area = 0.0f;
            #pragma unroll
            for (int di = 0; di < 3; ++di) {
                float bl = (float)(lx0 + di);
                float ox = fmaxf(fminf(xmaxl, bl + 1.0f) - fmaxf(mxl, bl), 0.0f);
                #pragma unroll
                for (int dj = 0; dj < 3; ++dj) {
                    float bly = (float)(ly0 + dj);
                    float oy  = fmaxf(fminf(ymaxl, bly + 1.0f) - fmaxf(myl, bly), 0.0f);
                    area += ox * oy * adjf[(lx0 + di) * LSTRIDE + (ly0 + dj)];
                }
            }
            out[p.z] = area;
        }
    }
}

// ---------------------------------------------------------------------------
// Fallback path (tiny workspace): direct global-atomic scatter + direct gather
// ---------------------------------------------------------------------------
__global__ void __launch_bounds__(256)
scatter_pin(const float* __restrict__ pos, const float* __restrict__ nsx,
            const float* __restrict__ nsy, const int* __restrict__ pw,
            float* __restrict__ pmap) {
    int i = blockIdx.x * blockDim.x + threadIdx.x;
    if (i >= NUM_PHYS) return;
    float sx = nsx[i], sy = nsy[i];
    float hx = 0.5f * fmaxf(1.414f, sx);
    float hy = 0.5f * fmaxf(1.414f, sy);
    float cx = pos[i] + 0.5f * sx;
    float cy = pos[NUM_NODES + i] + 0.5f * sy;
    float xmin = cx - hx, xmax = cx + hx;
    float ymin = cy - hy, ymax = cy + hy;
    float dens = (float)pw[i] / (4.0f * hx * hy);
    int bxl = min(max((int)floorf(xmin), 0), NBX - 1);
    int byl = min(max((int)floorf(ymin), 0), NBY - 1);
    #pragma unroll
    for (int di = 0; di < 3; ++di) {
        float bl = (float)(bxl + di);
        float ox = fminf(xmax, bl + 1.0f) - fmaxf(xmin, bl);
        if (ox <= 0.0f) continue;
        float dox = dens * ox;
        int base = min(bxl + di, NBX - 1) * NBY;
        #pragma unroll
        for (int dj = 0; dj < 3; ++dj) {
            float bly = (float)(byl + dj);
            float oy  = fminf(ymax, bly + 1.0f) - fmaxf(ymin, bly);
            if (oy > 0.0f) atomicAdd(&pmap[base + min(byl + dj, NBY - 1)], dox * oy);
        }
    }
}

__device__ __forceinline__ float gather_one(const float* __restrict__ pos,
                                            const float* __restrict__ nsx,
                                            const float* __restrict__ nsy,
                                            const float* __restrict__ pmap,
                                            int i) {
    float mx = pos[i];
    float my = pos[NUM_NODES + i];
    float xmax = mx + nsx[i];
    float ymax = my + nsy[i];
    int bxl = min(max((int)floorf(mx), 0), NBX - 1);
    int byl = min(max((int)floorf(my), 0), NBY - 1);
    float ox[3], oy[3];
    int rowb[3], colb[3];
    #pragma unroll
    for (int d = 0; d < 3; ++d) {
        float bl  = (float)(bxl + d);
        float bly = (float)(byl + d);
        ox[d] = fmaxf(fminf(xmax, bl + 1.0f) - fmaxf(mx, bl), 0.0f);
        oy[d] = fmaxf(fminf(ymax, bly + 1.0f) - fmaxf(my, bly), 0.0f);
        rowb[d] = min(bxl + d, NBX - 1) * NBY;
        colb[d] = min(byl + d, NBY - 1);
    }
    float area = 0.0f;
    #pragma unroll
    for (int di = 0; di < 3; ++di)
        #pragma unroll
        for (int dj = 0; dj < 3; ++dj) {
            float a = fminf(fmaxf(pmap[rowb[di] + colb[dj]] * 0.5f, 0.4f), 2.5f);
            area += ox[di] * oy[dj] * a;
        }
    return area;
}

__global__ void __launch_bounds__(256)
gather_area(const float* __restrict__ pos, const float* __restrict__ nsx,
            const float* __restrict__ nsy, const float* __restrict__ pmap,
            float* __restrict__ out) {
    int i = blockIdx.x * blockDim.x + threadIdx.x;
    if (i >= HALF_MOV) return;
    int i2 = i + HALF_MOV;
    float a1 = gather_one(pos, nsx, nsy, pmap, i);
    float a2 = gather_one(pos, nsx, nsy, pmap, i2);
    out[i]  = a1;
    out[i2] = a2;
}

// ---------------------------------------------------------------------------
extern "C" void kernel_launch(void* const* d_in, const int* in_sizes, int n_in,
                              void* d_out, int out_size, void* d_ws, size_t ws_size,
                              hipStream_t stream) {
    const float* pos = (const float*)d_in[0];
    const float* nsx = (const float*)d_in[1];
    const float* nsy = (const float*)d_in[2];
    const int*   pw  = (const int*)d_in[3];
    float* out = (float*)d_out;

    char* ws = (char*)d_ws;
    float*    pmap  = (float*)(ws + OFF_PMAP);
    unsigned* curs  = (unsigned*)(ws + OFF_CURS);
    unsigned* cursm = (unsigned*)(ws + OFF_CURSM);
    unsigned* curh  = (unsigned*)(ws + OFF_CURH);
    uint2*    slab  = (uint2*)(ws + OFF_SLAB);
    uint3*    mslab = (uint3*)(ws + OFF_MSLAB);
    uint2*    hslab = (uint2*)(ws + OFF_HSLAB);

    if (ws_size >= WS_FULL) {
        // zero the three cursor arrays only (3 KB)
        hipMemsetAsync(ws + OFF_CURS, 0, OFF_SLAB - OFF_CURS, stream);
        int grid = (NUM_PHYS + FB_CHUNK - 1) / FB_CHUNK;   // 733
        fill_both<<<grid, FB_BLOCK, 0, stream>>>(pos, nsx, nsy, pw,
                                                 curs, cursm, curh,
                                                 slab, mslab, hslab);
        fused_bc <<<NTILES, 1024, 0, stream>>>(slab, curs, hslab, curh,
                                               mslab, cursm, out);
    } else {
        hipMemsetAsync(pmap, 0, (size_t)NBX * NBY * sizeof(float), stream);
        scatter_pin <<<(NUM_PHYS + 255) / 256, 256, 0, stream>>>(pos, nsx, nsy, pw, pmap);
        gather_area <<<(HALF_MOV + 255) / 256, 256, 0, stream>>>(pos, nsx, nsy, pmap, out);
    }
}